// Round 12
// baseline (159.607 us; speedup 1.0000x reference)
//
#include <hip/hip_runtime.h>
#include <hip/hip_bf16.h>
#include <stdint.h>

#define B_SZ 1024
#define N_SZ 65536
#define M_SZ 128

typedef short bf16x8 __attribute__((ext_vector_type(8)));
typedef short bf16x4 __attribute__((ext_vector_type(4)));
typedef float f32x4 __attribute__((ext_vector_type(4)));

__device__ __forceinline__ unsigned short f2bf(float f) {
    uint32_t u = __float_as_uint(f);
    uint32_t r = (u + 0x7FFFu + ((u >> 16) & 1u)) >> 16;  // RNE
    return (unsigned short)r;
}

// lgkm-only barrier: LDS deps drained; VMEM (gl_lds / prefetch) stays in flight.
#define BAR() { asm volatile("s_waitcnt lgkmcnt(0)" ::: "memory"); __builtin_amdgcn_s_barrier(); }

// ---- kernel 0: EDt[c][b] bf16, c<128 -> E[b][c], else D[b][c-128]. [256][1024]
__global__ __launch_bounds__(256) void k_edt(const float* __restrict__ E,
                                             const float* __restrict__ D,
                                             unsigned short* __restrict__ EDt) {
    __shared__ float tile[32][33];
    int bx = blockIdx.x & 31;
    int cy = blockIdx.x >> 5;
    int b0 = bx * 32, c0 = cy * 32;
    const float* src = (c0 < M_SZ) ? E : D;
    int cs0 = c0 & (M_SZ - 1);
    int t = threadIdx.x;
    int i = t >> 3, j = (t & 7) * 4;
    const float* p = src + (size_t)(b0 + i) * M_SZ + cs0 + j;
    float4 v = *(const float4*)p;
    tile[i][j] = v.x; tile[i][j + 1] = v.y; tile[i][j + 2] = v.z; tile[i][j + 3] = v.w;
    __syncthreads();
    int c = t >> 3, b4 = (t & 7) * 4;
    unsigned short* q = EDt + (size_t)(c0 + c) * B_SZ + b0 + b4;
    ushort4 o;
    o.x = f2bf(tile[b4 + 0][c]); o.y = f2bf(tile[b4 + 1][c]);
    o.z = f2bf(tile[b4 + 2][c]); o.w = f2bf(tile[b4 + 3][c]);
    *(ushort4*)q = o;
}

// =======================  PASS 1  =======================
// R11 structure + T4 counted-vmcnt/raw-barrier pipeline.
// Steady body: 16 VMEM outstanding at compute; gl_lds(cur) = oldest 4 -> vmcnt(12).
#define AS_LD 132

__global__ __launch_bounds__(256, 2) void k_pass1(
    const float* __restrict__ A,            // [B][N]
    const unsigned short* __restrict__ EDt, // [256][B] bf16
    const float* __restrict__ C,            // [N][M]
    unsigned short* __restrict__ NCt)       // [M][N] bf16 out (transposed)
{
    __shared__ __align__(16) unsigned short As[2][32 * AS_LD];
    __shared__ __align__(16) unsigned short EDs[2][256 * 32];
    const int t = threadIdx.x;
    const int lane = t & 63;
    const int wv = t >> 6;
    const int wvn = wv >> 1, wvc = wv & 1;
    const int g = lane >> 4;
    const int m16 = lane & 15;
    const int n0 = blockIdx.x * 128;

    const int kb = t >> 3;
    const int cA = (t & 7) * 16;

    int cb[8];
#pragma unroll
    for (int fj = 0; fj < 4; ++fj) { cb[fj] = wvc * 4 + fj; cb[fj + 4] = 8 + wvc * 4 + fj; }

    f32x4 acc[4][8];
#pragma unroll
    for (int i = 0; i < 4; ++i)
#pragma unroll
        for (int j = 0; j < 8; ++j) acc[i][j] = (f32x4){0.f, 0.f, 0.f, 0.f};

#define ED_GLLDS(buf, bkv)                                                          \
    {                                                                               \
        _Pragma("unroll")                                                           \
        for (int i_ = 0; i_ < 4; ++i_) {                                            \
            int L_ = i_ * 256 + t;                                                  \
            int col_ = L_ >> 2;                                                     \
            int ss_ = (L_ & 3) ^ ((col_ >> 1) & 3);                                 \
            const unsigned short* gsrc_ = EDt + (size_t)col_ * B_SZ + (bkv) + ss_ * 8; \
            __builtin_amdgcn_global_load_lds(                                       \
                (const __attribute__((address_space(1))) uint32_t*)(const void*)gsrc_, \
                (__attribute__((address_space(3))) uint32_t*)(void*)&EDs[buf][(i_ * 256 + wv * 64) * 8], \
                16, 0, 0);                                                          \
        }                                                                           \
    }

#define A_LOAD(dst0, dst1, dst2, dst3, bkv)                                         \
    {                                                                               \
        const float* p_ = A + (size_t)((bkv) + kb) * N_SZ + n0 + cA;                \
        dst0 = ((const float4*)p_)[0]; dst1 = ((const float4*)p_)[1];               \
        dst2 = ((const float4*)p_)[2]; dst3 = ((const float4*)p_)[3];               \
    }

#define A_WRITE(buf, s0, s1, s2, s3)                                                \
    {                                                                               \
        ushort4* w_ = (ushort4*)&As[buf][kb * AS_LD + cA];                          \
        ushort4 o_;                                                                 \
        o_.x = f2bf(s0.x); o_.y = f2bf(s0.y); o_.z = f2bf(s0.z); o_.w = f2bf(s0.w); w_[0] = o_; \
        o_.x = f2bf(s1.x); o_.y = f2bf(s1.y); o_.z = f2bf(s1.z); o_.w = f2bf(s1.w); w_[1] = o_; \
        o_.x = f2bf(s2.x); o_.y = f2bf(s2.y); o_.z = f2bf(s2.z); o_.w = f2bf(s2.w); w_[2] = o_; \
        o_.x = f2bf(s3.x); o_.y = f2bf(s3.y); o_.z = f2bf(s3.z); o_.w = f2bf(s3.w); w_[3] = o_; \
    }

#define P1_COMPUTE(buf, VM)                                                         \
    {                                                                               \
        asm volatile("s_waitcnt vmcnt(" #VM ")" ::: "memory");                      \
        __builtin_amdgcn_sched_barrier(0);                                          \
        bf16x8 af_[4];                                                              \
        _Pragma("unroll")                                                           \
        for (int fi = 0; fi < 4; ++fi) {                                            \
            int nl_ = wvn * 64 + fi * 16 + m16;                                     \
            _Pragma("unroll")                                                       \
            for (int j = 0; j < 8; ++j)                                             \
                af_[fi][j] = (short)As[buf][(g * 8 + j) * AS_LD + nl_];              \
        }                                                                           \
        bf16x8 bfr_[8];                                                             \
        _Pragma("unroll")                                                           \
        for (int fj = 0; fj < 8; ++fj) {                                            \
            int col_ = cb[fj] * 16 + m16;                                           \
            bfr_[fj] = *(const bf16x8*)&EDs[buf][col_ * 32 + ((g ^ ((col_ >> 1) & 3)) << 3)]; \
        }                                                                           \
        _Pragma("unroll")                                                           \
        for (int fj = 0; fj < 8; ++fj)                                              \
            _Pragma("unroll")                                                       \
            for (int fi = 0; fi < 4; ++fi)                                          \
                acc[fi][fj] = __builtin_amdgcn_mfma_f32_16x16x32_bf16(af_[fi], bfr_[fj], acc[fi][fj], 0, 0, 0); \
    }

    float4 ra0_0, ra0_1, ra0_2, ra0_3;
    float4 ra1_0, ra1_1, ra1_2, ra1_3;

    // prologue: after BAR, outstanding = gl_lds(0,chunk0):4 + ra1(chunk1):4 = 8
    A_LOAD(ra0_0, ra0_1, ra0_2, ra0_3, 0)
    ED_GLLDS(0, 0)
    A_WRITE(0, ra0_0, ra0_1, ra0_2, ra0_3)
    A_LOAD(ra1_0, ra1_1, ra1_2, ra1_3, 32)
    BAR()

    // steady bodies 0..29 (15 pairs): every body issues 4 gl_lds + 4 A-loads
    for (int c = 0; c < 30; c += 2) {
        ED_GLLDS(1, (c + 1) * 32)
        A_LOAD(ra0_0, ra0_1, ra0_2, ra0_3, (c + 2) * 32)
        P1_COMPUTE(0, 12)
        A_WRITE(1, ra1_0, ra1_1, ra1_2, ra1_3)
        BAR()
        ED_GLLDS(0, (c + 2) * 32)
        A_LOAD(ra1_0, ra1_1, ra1_2, ra1_3, (c + 3) * 32)
        P1_COMPUTE(1, 12)
        A_WRITE(0, ra0_0, ra0_1, ra0_2, ra0_3)
        BAR()
    }
    // body 30: outstanding = gl_lds(0,30):4 + ra1(31):4 + new gl_lds(1,31):4 = 12 -> vmcnt(8)
    ED_GLLDS(1, 31 * 32)
    P1_COMPUTE(0, 8)
    A_WRITE(1, ra1_0, ra1_1, ra1_2, ra1_3)
    BAR()
    // body 31: only gl_lds(1,31) possibly pending -> vmcnt(0)
    P1_COMPUTE(1, 0)

    // epilogue (register + global only)
#pragma unroll
    for (int fi = 0; fi < 4; ++fi)
#pragma unroll
        for (int fj = 0; fj < 4; ++fj) {
            int n_base = n0 + wvn * 64 + fi * 16 + g * 4;
            int m = wvc * 64 + fj * 16 + m16;
            bf16x4 o;
#pragma unroll
            for (int r = 0; r < 4; ++r) {
                float w = acc[fi][fj][r];
                float v = acc[fi][fj + 4][r];
                float cc = C[(size_t)(n_base + r) * M_SZ + m];
                o[r] = (short)f2bf(cc * (1.0f - w) + v);
            }
            *(bf16x4*)&NCt[(size_t)m * N_SZ + n_base] = o;
        }
}

// =======================  PASS 2  =======================
// R11 structure + T4. Steady: 12 outstanding at compute; gl_lds(cur)=oldest 2 -> vmcnt(10).
#define L2_LD 40

__global__ __launch_bounds__(256, 2) void k_pass2(
    const float* __restrict__ A,
    const unsigned short* __restrict__ NCt,  // [M][N]
    float* __restrict__ part)                // [64][B][M] f32 partials
{
    __shared__ __align__(16) unsigned short As2[2][128 * L2_LD];
    __shared__ __align__(16) unsigned short NCs[2][128 * 32];
    const int t = threadIdx.x;
    const int lane = t & 63;
    const int wv = t >> 6;
    const int wvb = wv >> 1, wvm = wv & 1;
    const int g = lane >> 4;
    const int m16 = lane & 15;
    const int b0 = (blockIdx.x & 7) * 128;
    const int ks = blockIdx.x >> 3;
    const int k0 = ks << 10;

    const int row = t >> 1, half = t & 1;

    f32x4 acc[4][4];
#pragma unroll
    for (int i = 0; i < 4; ++i)
#pragma unroll
        for (int j = 0; j < 4; ++j) acc[i][j] = (f32x4){0.f, 0.f, 0.f, 0.f};

#define NC_GLLDS(buf, kkv)                                                          \
    {                                                                               \
        _Pragma("unroll")                                                           \
        for (int i_ = 0; i_ < 2; ++i_) {                                            \
            int L_ = i_ * 256 + t;                                                  \
            int row_ = L_ >> 2;                                                     \
            int ss_ = (L_ & 3) ^ ((row_ >> 1) & 3);                                 \
            const unsigned short* gsrc_ = NCt + (size_t)row_ * N_SZ + k0 + (kkv) + ss_ * 8; \
            __builtin_amdgcn_global_load_lds(                                       \
                (const __attribute__((address_space(1))) uint32_t*)(const void*)gsrc_, \
                (__attribute__((address_space(3))) uint32_t*)(void*)&NCs[buf][L_ * 8], \
                16, 0, 0);                                                          \
        }                                                                           \
    }

#define A2_LOAD(dst0, dst1, dst2, dst3, kkv)                                        \
    {                                                                               \
        const float* p_ = A + (size_t)(b0 + row) * N_SZ + k0 + (kkv) + half * 16;   \
        dst0 = ((const float4*)p_)[0]; dst1 = ((const float4*)p_)[1];               \
        dst2 = ((const float4*)p_)[2]; dst3 = ((const float4*)p_)[3];               \
    }

#define A2_WRITE(buf, s0, s1, s2, s3)                                               \
    {                                                                               \
        ushort4* w_ = (ushort4*)&As2[buf][row * L2_LD + half * 16];                 \
        ushort4 o_;                                                                 \
        o_.x = f2bf(s0.x); o_.y = f2bf(s0.y); o_.z = f2bf(s0.z); o_.w = f2bf(s0.w); w_[0] = o_; \
        o_.x = f2bf(s1.x); o_.y = f2bf(s1.y); o_.z = f2bf(s1.z); o_.w = f2bf(s1.w); w_[1] = o_; \
        o_.x = f2bf(s2.x); o_.y = f2bf(s2.y); o_.z = f2bf(s2.z); o_.w = f2bf(s2.w); w_[2] = o_; \
        o_.x = f2bf(s3.x); o_.y = f2bf(s3.y); o_.z = f2bf(s3.z); o_.w = f2bf(s3.w); w_[3] = o_; \
    }

#define P2_COMPUTE(buf, VM)                                                         \
    {                                                                               \
        asm volatile("s_waitcnt vmcnt(" #VM ")" ::: "memory");                      \
        __builtin_amdgcn_sched_barrier(0);                                          \
        bf16x8 af_[4];                                                              \
        _Pragma("unroll")                                                           \
        for (int fi = 0; fi < 4; ++fi)                                              \
            af_[fi] = *(const bf16x8*)&As2[buf][(wvb * 64 + fi * 16 + m16) * L2_LD + g * 8]; \
        bf16x8 bfr_[4];                                                             \
        _Pragma("unroll")                                                           \
        for (int fj = 0; fj < 4; ++fj) {                                            \
            int row_ = wvm * 64 + fj * 16 + m16;                                    \
            bfr_[fj] = *(const bf16x8*)&NCs[buf][row_ * 32 + ((g ^ ((row_ >> 1) & 3)) << 3)]; \
        }                                                                           \
        _Pragma("unroll")                                                           \
        for (int fi = 0; fi < 4; ++fi)                                              \
            _Pragma("unroll")                                                       \
            for (int fj = 0; fj < 4; ++fj)                                          \
                acc[fi][fj] = __builtin_amdgcn_mfma_f32_16x16x32_bf16(af_[fi], bfr_[fj], acc[fi][fj], 0, 0, 0); \
    }

    float4 rb0_0, rb0_1, rb0_2, rb0_3;
    float4 rb1_0, rb1_1, rb1_2, rb1_3;

    // prologue: after BAR, outstanding = gl_lds(0):2 + rb1(chunk1):4 = 6
    A2_LOAD(rb0_0, rb0_1, rb0_2, rb0_3, 0)
    NC_GLLDS(0, 0)
    A2_WRITE(0, rb0_0, rb0_1, rb0_2, rb0_3)
    A2_LOAD(rb1_0, rb1_1, rb1_2, rb1_3, 32)
    BAR()

    for (int c = 0; c < 30; c += 2) {
        NC_GLLDS(1, (c + 1) * 32)
        A2_LOAD(rb0_0, rb0_1, rb0_2, rb0_3, (c + 2) * 32)
        P2_COMPUTE(0, 10)
        A2_WRITE(1, rb1_0, rb1_1, rb1_2, rb1_3)
        BAR()
        NC_GLLDS(0, (c + 2) * 32)
        A2_LOAD(rb1_0, rb1_1, rb1_2, rb1_3, (c + 3) * 32)
        P2_COMPUTE(1, 10)
        A2_WRITE(0, rb0_0, rb0_1, rb0_2, rb0_3)
        BAR()
    }
    // body 30: outstanding = gl_lds(0,30):2 + rb1(31):4 + gl_lds(1,31):2 = 8 -> vmcnt(6)
    NC_GLLDS(1, 31 * 32)
    P2_COMPUTE(0, 6)
    A2_WRITE(1, rb1_0, rb1_1, rb1_2, rb1_3)
    BAR()
    P2_COMPUTE(1, 0)

    float* pp = part + (size_t)ks * (B_SZ * M_SZ);
#pragma unroll
    for (int fi = 0; fi < 4; ++fi)
#pragma unroll
        for (int fj = 0; fj < 4; ++fj)
#pragma unroll
            for (int r = 0; r < 4; ++r) {
                int b = b0 + wvb * 64 + fi * 16 + g * 4 + r;
                int m = wvm * 64 + fj * 16 + m16;
                pp[(size_t)b * M_SZ + m] = acc[fi][fj][r];
            }
}

// ---- reduce: out[b][m] = sum_{s<64} part[s][b][m].  128 blocks x 256 thr x float4.
__global__ __launch_bounds__(256) void k_reduce(const float* __restrict__ part,
                                                float* __restrict__ out) {
    const int idx4 = blockIdx.x * 256 + threadIdx.x;   // 0..32767
    const float* p = part + (size_t)idx4 * 4;
    f32x4 s0 = {0.f,0.f,0.f,0.f}, s1 = s0, s2 = s0, s3 = s0;
#pragma unroll
    for (int s = 0; s < 64; s += 4) {
        f32x4 v0 = *(const f32x4*)(p + (size_t)(s + 0) * (B_SZ * M_SZ));
        f32x4 v1 = *(const f32x4*)(p + (size_t)(s + 1) * (B_SZ * M_SZ));
        f32x4 v2 = *(const f32x4*)(p + (size_t)(s + 2) * (B_SZ * M_SZ));
        f32x4 v3 = *(const f32x4*)(p + (size_t)(s + 3) * (B_SZ * M_SZ));
        s0 += v0; s1 += v1; s2 += v2; s3 += v3;
    }
    f32x4 r = (s0 + s1) + (s2 + s3);
    *(f32x4*)(out + (size_t)idx4 * 4) = r;
}

extern "C" void kernel_launch(void* const* d_in, const int* in_sizes, int n_in,
                              void* d_out, int out_size, void* d_ws, size_t ws_size,
                              hipStream_t stream) {
    const float* A  = (const float*)d_in[0];   // address [B,N]
    const float* E  = (const float*)d_in[1];   // erase   [B,M]
    const float* Dd = (const float*)d_in[2];   // add     [B,M]
    const float* C  = (const float*)d_in[3];   // content [N,M]
    float* out = (float*)d_out;

    unsigned short* NCt = (unsigned short*)d_ws;                                      // 16 MB [M][N]
    unsigned short* EDt = (unsigned short*)((char*)d_ws + (size_t)M_SZ * N_SZ * 2);   // +512 KB
    float* part = (float*)((char*)d_ws + (size_t)M_SZ * N_SZ * 2 + (size_t)256 * B_SZ * 2); // +32 MB

    k_edt   <<<256, 256, 0, stream>>>(E, Dd, EDt);
    k_pass1 <<<512, 256, 0, stream>>>(A, EDt, C, NCt);
    k_pass2 <<<512, 256, 0, stream>>>(A, NCt, part);
    k_reduce<<<128, 256, 0, stream>>>(part, out);
}

// Round 13
// 149.638 us; speedup vs baseline: 1.0666x; 1.0666x over previous
//
#include <hip/hip_runtime.h>
#include <hip/hip_bf16.h>
#include <stdint.h>

#define B_SZ 1024
#define N_SZ 65536
#define M_SZ 128

typedef short bf16x8 __attribute__((ext_vector_type(8)));
typedef short bf16x4 __attribute__((ext_vector_type(4)));
typedef float f32x4 __attribute__((ext_vector_type(4)));

__device__ __forceinline__ unsigned short f2bf(float f) {
    uint32_t u = __float_as_uint(f);
    uint32_t r = (u + 0x7FFFu + ((u >> 16) & 1u)) >> 16;  // RNE
    return (unsigned short)r;
}

// ---- kernel 0: EDt[c][b] bf16, c<128 -> E[b][c], else D[b][c-128]. [256][1024]
__global__ __launch_bounds__(256) void k_edt(const float* __restrict__ E,
                                             const float* __restrict__ D,
                                             unsigned short* __restrict__ EDt) {
    __shared__ float tile[32][33];
    int bx = blockIdx.x & 31;
    int cy = blockIdx.x >> 5;
    int b0 = bx * 32, c0 = cy * 32;
    const float* src = (c0 < M_SZ) ? E : D;
    int cs0 = c0 & (M_SZ - 1);
    int t = threadIdx.x;
    int i = t >> 3, j = (t & 7) * 4;
    const float* p = src + (size_t)(b0 + i) * M_SZ + cs0 + j;
    float4 v = *(const float4*)p;
    tile[i][j] = v.x; tile[i][j + 1] = v.y; tile[i][j + 2] = v.z; tile[i][j + 3] = v.w;
    __syncthreads();
    int c = t >> 3, b4 = (t & 7) * 4;
    unsigned short* q = EDt + (size_t)(c0 + c) * B_SZ + b0 + b4;
    ushort4 o;
    o.x = f2bf(tile[b4 + 0][c]); o.y = f2bf(tile[b4 + 1][c]);
    o.z = f2bf(tile[b4 + 2][c]); o.w = f2bf(tile[b4 + 3][c]);
    *(ushort4*)q = o;
}

// =======================  PASS 1  =======================
// NCt[m][n] = C[n][m]*(1-W) + V,  (W|V) = A^T @ (E||D)
// A tile: k-pair packed As32[128 n][20 u32] (u32 p = bf16 pair kb=2p,2p+1).
//   stage: thread (n=t&127, h=t>>7) -> 16 coalesced scalar loads A[h*16+j][n],
//          pack 8 u32, 2 linear b128 writes at [n*20 + h*8]. pad-20 -> 2-way free.
//   frag:  af[fi] = ONE b128 at [n*20 + g*4]  (kb = g*8..+8, lo/hi = k order).
// ED: global_load_lds w16 (R10-proven swizzle pair). Barriers: plain __syncthreads.
#define AS_W 20

__global__ __launch_bounds__(256, 2) void k_pass1(
    const float* __restrict__ A,            // [B][N]
    const unsigned short* __restrict__ EDt, // [256][B] bf16
    const float* __restrict__ C,            // [N][M]
    unsigned short* __restrict__ NCt)       // [M][N] bf16 out (transposed)
{
    __shared__ __align__(16) uint32_t As32[2][128 * AS_W];
    __shared__ __align__(16) unsigned short EDs[2][256 * 32];
    const int t = threadIdx.x;
    const int lane = t & 63;
    const int wv = t >> 6;
    const int wvn = wv >> 1, wvc = wv & 1;
    const int g = lane >> 4;
    const int m16 = lane & 15;
    const int n0 = blockIdx.x * 128;

    const int nn = t & 127;         // A staging: n column
    const int hh = t >> 7;          // A staging: k-half (kb = hh*16 .. +16)

    int cb[8];
#pragma unroll
    for (int fj = 0; fj < 4; ++fj) { cb[fj] = wvc * 4 + fj; cb[fj + 4] = 8 + wvc * 4 + fj; }

    f32x4 acc[4][8];
#pragma unroll
    for (int i = 0; i < 4; ++i)
#pragma unroll
        for (int j = 0; j < 8; ++j) acc[i][j] = (f32x4){0.f, 0.f, 0.f, 0.f};

#define ED_GLLDS(buf, bkv)                                                          \
    {                                                                               \
        _Pragma("unroll")                                                           \
        for (int i_ = 0; i_ < 4; ++i_) {                                            \
            int L_ = i_ * 256 + t;                                                  \
            int col_ = L_ >> 2;                                                     \
            int ss_ = (L_ & 3) ^ ((col_ >> 1) & 3);                                 \
            const unsigned short* gsrc_ = EDt + (size_t)col_ * B_SZ + (bkv) + ss_ * 8; \
            __builtin_amdgcn_global_load_lds(                                       \
                (const __attribute__((address_space(1))) uint32_t*)(const void*)gsrc_, \
                (__attribute__((address_space(3))) uint32_t*)(void*)&EDs[buf][(i_ * 256 + wv * 64) * 8], \
                16, 0, 0);                                                          \
        }                                                                           \
    }

    // 16 coalesced scalar loads: v[j] = A[bkv + hh*16 + j][n0 + nn]
#define A_LOAD(dst, bkv)                                                            \
    {                                                                               \
        const float* p_ = A + (size_t)((bkv) + hh * 16) * N_SZ + n0 + nn;           \
        _Pragma("unroll")                                                           \
        for (int j_ = 0; j_ < 16; ++j_)                                             \
            dst[j_] = p_[(size_t)j_ * N_SZ];                                        \
    }

    // pack 8 k-pair u32, 2 linear b128 writes
#define A_WRITE(buf, src)                                                           \
    {                                                                               \
        uint32_t pk_[8];                                                            \
        _Pragma("unroll")                                                           \
        for (int p_ = 0; p_ < 8; ++p_)                                              \
            pk_[p_] = (uint32_t)f2bf(src[2 * p_]) | ((uint32_t)f2bf(src[2 * p_ + 1]) << 16); \
        uint4* w_ = (uint4*)&As32[buf][nn * AS_W + hh * 8];                          \
        w_[0] = (uint4){pk_[0], pk_[1], pk_[2], pk_[3]};                            \
        w_[1] = (uint4){pk_[4], pk_[5], pk_[6], pk_[7]};                            \
    }

#define P1_COMPUTE(buf)                                                             \
    {                                                                               \
        bf16x8 af_[4];                                                              \
        _Pragma("unroll")                                                           \
        for (int fi = 0; fi < 4; ++fi) {                                            \
            int nl_ = wvn * 64 + fi * 16 + m16;                                     \
            af_[fi] = *(const bf16x8*)&As32[buf][nl_ * AS_W + g * 4];                \
        }                                                                           \
        bf16x8 bfr_[8];                                                             \
        _Pragma("unroll")                                                           \
        for (int fj = 0; fj < 8; ++fj) {                                            \
            int col_ = cb[fj] * 16 + m16;                                           \
            bfr_[fj] = *(const bf16x8*)&EDs[buf][col_ * 32 + ((g ^ ((col_ >> 1) & 3)) << 3)]; \
        }                                                                           \
        _Pragma("unroll")                                                           \
        for (int fj = 0; fj < 8; ++fj)                                              \
            _Pragma("unroll")                                                       \
            for (int fi = 0; fi < 4; ++fi)                                          \
                acc[fi][fj] = __builtin_amdgcn_mfma_f32_16x16x32_bf16(af_[fi], bfr_[fj], acc[fi][fj], 0, 0, 0); \
    }

    float ra0[16], ra1[16];   // depth-2 named slots (all indices static)

    // prologue: chunk0 -> buf0; chunk1 -> ra1
    A_LOAD(ra0, 0)
    ED_GLLDS(0, 0)
    A_WRITE(0, ra0)
    A_LOAD(ra1, 32)
    __syncthreads();

    for (int c = 0; c < 32; c += 2) {
        if (c + 1 < 32) ED_GLLDS(1, (c + 1) * 32)
        if (c + 2 < 32) A_LOAD(ra0, (c + 2) * 32)
        P1_COMPUTE(0)
        if (c + 1 < 32) A_WRITE(1, ra1)
        __syncthreads();
        if (c + 1 < 32) {
            if (c + 2 < 32) ED_GLLDS(0, (c + 2) * 32)
            if (c + 3 < 32) A_LOAD(ra1, (c + 3) * 32)
            P1_COMPUTE(1)
            if (c + 2 < 32) A_WRITE(0, ra0)
            __syncthreads();
        }
    }

    // epilogue: D layout col=lane&15, row=(lane>>4)*4+r. NCt[m][n]: n contiguous.
#pragma unroll
    for (int fi = 0; fi < 4; ++fi)
#pragma unroll
        for (int fj = 0; fj < 4; ++fj) {
            int n_base = n0 + wvn * 64 + fi * 16 + g * 4;
            int m = wvc * 64 + fj * 16 + m16;
            bf16x4 o;
#pragma unroll
            for (int r = 0; r < 4; ++r) {
                float w = acc[fi][fj][r];
                float v = acc[fi][fj + 4][r];
                float cc = C[(size_t)(n_base + r) * M_SZ + m];
                o[r] = (short)f2bf(cc * (1.0f - w) + v);
            }
            *(bf16x4*)&NCt[(size_t)m * N_SZ + n_base] = o;
        }
}

// =======================  PASS 2  (verbatim R11 — at its HBM roofline) ==========
#define L2_LD 40

__global__ __launch_bounds__(256, 2) void k_pass2(
    const float* __restrict__ A,
    const unsigned short* __restrict__ NCt,  // [M][N]
    float* __restrict__ part)                // [64][B][M] f32 partials
{
    __shared__ __align__(16) unsigned short As2[2][128 * L2_LD];
    __shared__ __align__(16) unsigned short NCs[2][128 * 32];
    const int t = threadIdx.x;
    const int lane = t & 63;
    const int wv = t >> 6;
    const int wvb = wv >> 1, wvm = wv & 1;
    const int g = lane >> 4;
    const int m16 = lane & 15;
    const int b0 = (blockIdx.x & 7) * 128;
    const int ks = blockIdx.x >> 3;
    const int k0 = ks << 10;

    const int row = t >> 1, half = t & 1;

    f32x4 acc[4][4];
#pragma unroll
    for (int i = 0; i < 4; ++i)
#pragma unroll
        for (int j = 0; j < 4; ++j) acc[i][j] = (f32x4){0.f, 0.f, 0.f, 0.f};

#define NC_GLLDS(buf, kkv)                                                          \
    {                                                                               \
        _Pragma("unroll")                                                           \
        for (int i_ = 0; i_ < 2; ++i_) {                                            \
            int L_ = i_ * 256 + t;                                                  \
            int row_ = L_ >> 2;                                                     \
            int ss_ = (L_ & 3) ^ ((row_ >> 1) & 3);                                 \
            const unsigned short* gsrc_ = NCt + (size_t)row_ * N_SZ + k0 + (kkv) + ss_ * 8; \
            __builtin_amdgcn_global_load_lds(                                       \
                (const __attribute__((address_space(1))) uint32_t*)(const void*)gsrc_, \
                (__attribute__((address_space(3))) uint32_t*)(void*)&NCs[buf][L_ * 8], \
                16, 0, 0);                                                          \
        }                                                                           \
    }

#define A2_LOAD(dst0, dst1, dst2, dst3, kkv)                                        \
    {                                                                               \
        const float* p_ = A + (size_t)(b0 + row) * N_SZ + k0 + (kkv) + half * 16;   \
        dst0 = ((const float4*)p_)[0]; dst1 = ((const float4*)p_)[1];               \
        dst2 = ((const float4*)p_)[2]; dst3 = ((const float4*)p_)[3];               \
    }

#define A2_WRITE(buf, s0, s1, s2, s3)                                               \
    {                                                                               \
        ushort4* w_ = (ushort4*)&As2[buf][row * L2_LD + half * 16];                 \
        ushort4 o_;                                                                 \
        o_.x = f2bf(s0.x); o_.y = f2bf(s0.y); o_.z = f2bf(s0.z); o_.w = f2bf(s0.w); w_[0] = o_; \
        o_.x = f2bf(s1.x); o_.y = f2bf(s1.y); o_.z = f2bf(s1.z); o_.w = f2bf(s1.w); w_[1] = o_; \
        o_.x = f2bf(s2.x); o_.y = f2bf(s2.y); o_.z = f2bf(s2.z); o_.w = f2bf(s2.w); w_[2] = o_; \
        o_.x = f2bf(s3.x); o_.y = f2bf(s3.y); o_.z = f2bf(s3.z); o_.w = f2bf(s3.w); w_[3] = o_; \
    }

#define P2_COMPUTE(buf)                                                             \
    {                                                                               \
        bf16x8 af_[4];                                                              \
        _Pragma("unroll")                                                           \
        for (int fi = 0; fi < 4; ++fi)                                              \
            af_[fi] = *(const bf16x8*)&As2[buf][(wvb * 64 + fi * 16 + m16) * L2_LD + g * 8]; \
        bf16x8 bfr_[4];                                                             \
        _Pragma("unroll")                                                           \
        for (int fj = 0; fj < 4; ++fj) {                                            \
            int row_ = wvm * 64 + fj * 16 + m16;                                    \
            bfr_[fj] = *(const bf16x8*)&NCs[buf][row_ * 32 + ((g ^ ((row_ >> 1) & 3)) << 3)]; \
        }                                                                           \
        _Pragma("unroll")                                                           \
        for (int fi = 0; fi < 4; ++fi)                                              \
            _Pragma("unroll")                                                       \
            for (int fj = 0; fj < 4; ++fj)                                          \
                acc[fi][fj] = __builtin_amdgcn_mfma_f32_16x16x32_bf16(af_[fi], bfr_[fj], acc[fi][fj], 0, 0, 0); \
    }

    float4 rb0_0, rb0_1, rb0_2, rb0_3;
    float4 rb1_0, rb1_1, rb1_2, rb1_3;

    A2_LOAD(rb0_0, rb0_1, rb0_2, rb0_3, 0)
    NC_GLLDS(0, 0)
    A2_WRITE(0, rb0_0, rb0_1, rb0_2, rb0_3)
    A2_LOAD(rb1_0, rb1_1, rb1_2, rb1_3, 32)
    __syncthreads();

    for (int c = 0; c < 32; c += 2) {
        if (c + 1 < 32) NC_GLLDS(1, (c + 1) * 32)
        if (c + 2 < 32) A2_LOAD(rb0_0, rb0_1, rb0_2, rb0_3, (c + 2) * 32)
        P2_COMPUTE(0)
        if (c + 1 < 32) A2_WRITE(1, rb1_0, rb1_1, rb1_2, rb1_3)
        __syncthreads();
        if (c + 1 < 32) {
            if (c + 2 < 32) NC_GLLDS(0, (c + 2) * 32)
            if (c + 3 < 32) A2_LOAD(rb1_0, rb1_1, rb1_2, rb1_3, (c + 3) * 32)
            P2_COMPUTE(1)
            if (c + 2 < 32) A2_WRITE(0, rb0_0, rb0_1, rb0_2, rb0_3)
            __syncthreads();
        }
    }

    float* pp = part + (size_t)ks * (B_SZ * M_SZ);
#pragma unroll
    for (int fi = 0; fi < 4; ++fi)
#pragma unroll
        for (int fj = 0; fj < 4; ++fj)
#pragma unroll
            for (int r = 0; r < 4; ++r) {
                int b = b0 + wvb * 64 + fi * 16 + g * 4 + r;
                int m = wvm * 64 + fj * 16 + m16;
                pp[(size_t)b * M_SZ + m] = acc[fi][fj][r];
            }
}

// ---- reduce: out[b][m] = sum_{s<64} part[s][b][m].  128 blocks x 256 thr x float4.
__global__ __launch_bounds__(256) void k_reduce(const float* __restrict__ part,
                                                float* __restrict__ out) {
    const int idx4 = blockIdx.x * 256 + threadIdx.x;   // 0..32767
    const float* p = part + (size_t)idx4 * 4;
    f32x4 s0 = {0.f,0.f,0.f,0.f}, s1 = s0, s2 = s0, s3 = s0;
#pragma unroll
    for (int s = 0; s < 64; s += 4) {
        f32x4 v0 = *(const f32x4*)(p + (size_t)(s + 0) * (B_SZ * M_SZ));
        f32x4 v1 = *(const f32x4*)(p + (size_t)(s + 1) * (B_SZ * M_SZ));
        f32x4 v2 = *(const f32x4*)(p + (size_t)(s + 2) * (B_SZ * M_SZ));
        f32x4 v3 = *(const f32x4*)(p + (size_t)(s + 3) * (B_SZ * M_SZ));
        s0 += v0; s1 += v1; s2 += v2; s3 += v3;
    }
    f32x4 r = (s0 + s1) + (s2 + s3);
    *(f32x4*)(out + (size_t)idx4 * 4) = r;
}

extern "C" void kernel_launch(void* const* d_in, const int* in_sizes, int n_in,
                              void* d_out, int out_size, void* d_ws, size_t ws_size,
                              hipStream_t stream) {
    const float* A  = (const float*)d_in[0];   // address [B,N]
    const float* E  = (const float*)d_in[1];   // erase   [B,M]
    const float* Dd = (const float*)d_in[2];   // add     [B,M]
    const float* C  = (const float*)d_in[3];   // content [N,M]
    float* out = (float*)d_out;

    unsigned short* NCt = (unsigned short*)d_ws;                                      // 16 MB [M][N]
    unsigned short* EDt = (unsigned short*)((char*)d_ws + (size_t)M_SZ * N_SZ * 2);   // +512 KB
    float* part = (float*)((char*)d_ws + (size_t)M_SZ * N_SZ * 2 + (size_t)256 * B_SZ * 2); // +32 MB

    k_edt   <<<256, 256, 0, stream>>>(E, Dd, EDt);
    k_pass1 <<<512, 256, 0, stream>>>(A, EDt, C, NCt);
    k_pass2 <<<512, 256, 0, stream>>>(A, NCt, part);
    k_reduce<<<128, 256, 0, stream>>>(part, out);
}